// Round 20
// baseline (180.370 us; speedup 1.0000x reference)
//
#include <hip/hip_runtime.h>
#include <hip/hip_bf16.h>

// out[B,S,D_OUT] = x @ sign(W)^T + bias  ==  GEMM M=8192, N=4096, K=4096.
// Round 20: R19 + anti-phase stagger. 2 blocks/CU co-reside but start
// in-phase (same dispatch+prologue barrier) -> bistable phase-lock keeps
// both blocks' MFMA bursts coincident -> pipes serialize (sum: 167k MFMA +
// 150k LDS = 321k cyc/CU measured). One-time ~640cyc delay for the second
// co-resident (hw-bid >= 256) flips to the stable anti-phase state where
// block A's MFMA overlaps block B's reads. If pairing assumption is wrong,
// both sleep equally -> exact no-op. GEMM otherwise byte-identical to R18.

#define M_DIM 8192
#define N_DIM 4096
#define K_DIM 4096
#define BM 256
#define BN 256
#define BK 64
#define NT (K_DIM / BK)  // 64

typedef __attribute__((ext_vector_type(4))) int i32x4;

// ---------- fused conversion kernel ----------

__device__ __forceinline__ signed char sgn_i8(float f) {
    return (f > 0.f) ? 1 : ((f < 0.f) ? -1 : 0);
}

__global__ __launch_bounds__(256) void cvt_fused(
    const float* __restrict__ x, const float* __restrict__ w,
    signed char* __restrict__ xb, signed char* __restrict__ wb,
    float* __restrict__ scales) {
    const int b   = blockIdx.x;
    const int tid = threadIdx.x;

    if (b < M_DIM) {
        const float4* xr4 = reinterpret_cast<const float4*>(x + (long)b * K_DIM);
        __shared__ float red[4];
        float4 v[4];
        float mx = 0.f;
#pragma unroll
        for (int i = 0; i < 4; ++i) {
            v[i] = xr4[tid + i * 256];
            mx = fmaxf(mx, fmaxf(fmaxf(fabsf(v[i].x), fabsf(v[i].y)),
                                 fmaxf(fabsf(v[i].z), fabsf(v[i].w))));
        }
#pragma unroll
        for (int o = 1; o < 64; o <<= 1) mx = fmaxf(mx, __shfl_xor(mx, o));
        if ((tid & 63) == 0) red[tid >> 6] = mx;
        __syncthreads();
        float rmax = fmaxf(fmaxf(red[0], red[1]), fmaxf(red[2], red[3]));
        const float inv = (rmax > 0.f) ? (127.f / rmax) : 0.f;

        char4* qr = reinterpret_cast<char4*>(xb + (long)b * K_DIM);
#pragma unroll
        for (int i = 0; i < 4; ++i) {
            char4 c;
            c.x = (signed char)__float2int_rn(fminf(fmaxf(v[i].x * inv, -127.f), 127.f));
            c.y = (signed char)__float2int_rn(fminf(fmaxf(v[i].y * inv, -127.f), 127.f));
            c.z = (signed char)__float2int_rn(fminf(fmaxf(v[i].z * inv, -127.f), 127.f));
            c.w = (signed char)__float2int_rn(fminf(fmaxf(v[i].w * inv, -127.f), 127.f));
            qr[tid + i * 256] = c;
        }
        if (tid == 0) scales[b] = (rmax > 0.f) ? (rmax * (1.f / 127.f)) : 0.f;
    } else {
        const long i = (long)(b - M_DIM) * 256 + tid;  // vec16 index
        const float4* p = reinterpret_cast<const float4*>(w) + i * 4;
        int4 r;
        signed char* rc = (signed char*)&r;
#pragma unroll
        for (int k = 0; k < 4; ++k) {
            float4 vv = p[k];
            rc[k * 4 + 0] = sgn_i8(vv.x);
            rc[k * 4 + 1] = sgn_i8(vv.y);
            rc[k * 4 + 2] = sgn_i8(vv.z);
            rc[k * 4 + 3] = sgn_i8(vv.w);
        }
        reinterpret_cast<int4*>(wb)[i] = r;
    }
}

// ---------- async global->LDS ----------

__device__ __forceinline__ void GL16(const void* g, void* l) {
    __builtin_amdgcn_global_load_lds(
        (const __attribute__((address_space(1))) unsigned int*)g,
        (__attribute__((address_space(3))) unsigned int*)l, 16, 0, 0);
}

// ---------- inline-asm ds_read_b128 (i32x4) ----------

template<int OFS>
__device__ __forceinline__ i32x4 DSRI(const signed char* p) {
    i32x4 r;
    auto lp = (const __attribute__((address_space(3))) signed char*)p;
    asm volatile("ds_read_b128 %0, %1 offset:%2"
                 : "=&v"(r) : "v"(lp), "i"(OFS));
    return r;
}

#define BARRIER asm volatile("s_barrier" ::: "memory")
#define VMCNT0  asm volatile("s_waitcnt vmcnt(0)" ::: "memory")
#define VMCNT1  asm volatile("s_waitcnt vmcnt(1)" ::: "memory")
#define VMCNT3  asm volatile("s_waitcnt vmcnt(3)" ::: "memory")
#define LGKM0   asm volatile("s_waitcnt lgkmcnt(0)" ::: "memory")
#define LGKM2   asm volatile("s_waitcnt lgkmcnt(2)" ::: "memory")
#define SCHED0  __builtin_amdgcn_sched_barrier(0)
#define PRIO1   __builtin_amdgcn_s_setprio(1)
#define PRIO0   __builtin_amdgcn_s_setprio(0)

// 4-MFMA cell: 2 m-frags x 2 n-frags, K=64 in one MFMA each.
#define HC(MB, NB, Af, AOFS, Bf) \
    _Pragma("unroll") for (int m_ = 0; m_ < 2; ++m_) \
    _Pragma("unroll") for (int n_ = 0; n_ < 2; ++n_) \
        acc[(MB) + m_][(NB) + n_] = __builtin_amdgcn_mfma_i32_16x16x64_i8( \
            Af[(AOFS) + m_], Bf[n_], acc[(MB) + m_][(NB) + n_], 0, 0, 0)

// ---------- 256x256 4-phase i8 GEMM (R18 schedule + anti-phase stagger) ----
// 512 thr = 8 waves (2M x 4N); wave out 128x64 = 8x4 16x16 frags; 32 MFMA/tile.
// LDS: As/Bs [2][256 rows][64B] = 64 KiB total (2 blocks/CU co-resident).
// Swizzle: row r's logical 16B-chunk g at phys g ^ ((r>>1)&3); staged via
// inverse-swizzled global cols (linear GL16 dest), read with the same XOR.
// Phases and lgkm/vmcnt ledger identical to R18 (see that round's header).

__global__ __launch_bounds__(512, 2) void gemm256q(
    const signed char* __restrict__ A,   // [M][K] i8 (quantized x)
    const signed char* __restrict__ Bt,  // [N][K] i8 (sign weights)
    const float* __restrict__ scales,    // [M] rowmax/127
    const float* __restrict__ bias,      // [N]
    float* __restrict__ C)               // [M][N] fp32
{
    __shared__ __align__(16) signed char As[2][BM * BK];  // 2 x 16 KiB
    __shared__ __align__(16) signed char Bs[2][BN * BK];  // 2 x 16 KiB

    // ----- anti-phase stagger: second co-resident block (hw-bid >= 256)
    // delays ~640 cyc once, flipping the bistable phase-lock to anti-phase.
    if ((blockIdx.x >> 8) & 1) {
        int cnt;
        asm volatile(
            "s_mov_b32 %0, 64\n"
            "1:\n"
            "s_nop 7\n"
            "s_sub_u32 %0, %0, 1\n"
            "s_cmp_lg_u32 %0, 0\n"
            "s_cbranch_scc1 1b\n"
            : "=s"(cnt) :: "scc");
    }

    const int tid  = threadIdx.x;
    const int lane = tid & 63;
    const int w    = tid >> 6;
    const int wr   = w >> 2;
    const int wc   = w & 3;

    // T1: XCD-aware bijective swizzle (grid = 512, divisible by 8)
    int bid = blockIdx.x;
    const int cpx = gridDim.x >> 3;
    bid = (bid & 7) * cpx + (bid >> 3);
    const int ntile = N_DIM / BN;  // 16
    const long brow = (long)(bid / ntile) * BM;
    const long bcol = (long)(bid % ntile) * BN;

    // ----- staging: each GL16/wave = 16 rows x 64B; lane l -> row l>>2,
    // phys chunk l&3; global col chunk g = (l&3) ^ ((l>>3)&3)  [row>>1 swz].
    const int lrow  = lane >> 2;
    const int gcol  = ((lane & 3) ^ ((lane >> 3) & 3)) * 16;  // i8 elements
    const int rA03u = (w >> 2) * 128 + (w & 3) * 16;          // wave-uniform
    const int rB01u = (w >> 1) * 64 + (w & 1) * 16;
    const long gA03 = brow + rA03u + lrow;
    const long gB01 = bcol + rB01u + lrow;

#define GA03(BUF, KT) GL16(A  + (gA03)      * (long)K_DIM + (gcol + (KT)), &As[BUF][(rA03u)      * 64])
#define GA47(BUF, KT) GL16(A  + (gA03 + 64) * (long)K_DIM + (gcol + (KT)), &As[BUF][(rA03u + 64) * 64])
#define GB01(BUF, KT) GL16(Bt + (gB01)      * (long)K_DIM + (gcol + (KT)), &Bs[BUF][(rB01u)      * 64])
#define GB23(BUF, KT) GL16(Bt + (gB01 + 32) * (long)K_DIM + (gcol + (KT)), &Bs[BUF][(rB01u + 32) * 64])

    // ----- fragment reads: row = base + (lane&15), k-chunk g = lane>>4,
    // phys chunk = g ^ ((row>>1)&3) = (lane>>4) ^ ((lane>>1)&3)  [base%16==0].
    const int fr = lane & 15;
    const int fq = lane >> 4;
    const int pch = (fq ^ ((lane >> 1) & 3)) * 16;  // bytes
    const int aoffB = (wr * 128 + fr) * 64 + pch;
    const int boffB = (wc * 64 + fr) * 64 + pch;

    const signed char* pA0 = &As[0][aoffB];
    const signed char* pA1 = &As[1][aoffB];
    const signed char* pB0 = &Bs[0][boffB];
    const signed char* pB1 = &Bs[1][boffB];

    i32x4 acc[8][4];
#pragma unroll
    for (int m = 0; m < 8; ++m)
#pragma unroll
        for (int n = 0; n < 4; ++n) acc[m][n] = (i32x4){0, 0, 0, 0};

    i32x4 a03[4], a47[4], b01[2], b23[2];

    // ----- prologue: tile0 (4 GL16) + tile1's B01 (1 GL16) -----
    GA03(0, 0); GA47(0, 0); GB01(0, 0); GB23(0, 0);
    GB01(1, BK);
    VMCNT0;
    BARRIER;
    b01[0] = DSRI<0>(pB0);
    b01[1] = DSRI<1024>(pB0);

#define TILE_BODY(TT, CUR, NXT, pAc, pBc, pBn) { \
    const long kt1 = (long)((TT) + 1) * BK; \
    const long kt2 = (long)((TT) + 2) * BK; \
    const bool s1 = ((TT) + 1 < NT); \
    const bool s2 = ((TT) + 2 < NT); \
    /* ---- ph1 ---- */ \
    BARRIER; \
    if (s1) { GB23(NXT, kt1); } \
    a03[0] = DSRI<0>(pAc);    a03[1] = DSRI<1024>(pAc); \
    a03[2] = DSRI<2048>(pAc); a03[3] = DSRI<3072>(pAc); \
    LGKM2; SCHED0; \
    PRIO1; HC(0, 0, a03, 0, b01); PRIO0; SCHED0; \
    LGKM0; SCHED0; \
    PRIO1; HC(2, 0, a03, 2, b01); PRIO0; SCHED0; \
    b23[0] = DSRI<2048>(pBc); b23[1] = DSRI<3072>(pBc); \
    /* ---- ph2 ---- */ \
    BARRIER; \
    if (s1) { GA03(NXT, kt1); GA47(NXT, kt1); } \
    LGKM0; SCHED0; \
    PRIO1; HC(0, 2, a03, 0, b23); PRIO0; SCHED0; \
    a47[0] = DSRI<4096>(pAc); a47[1] = DSRI<5120>(pAc); \
    SCHED0; \
    PRIO1; HC(2, 2, a03, 2, b23); PRIO0; SCHED0; \
    a47[2] = DSRI<6144>(pAc); a47[3] = DSRI<7168>(pAc); \
    /* ---- ph3: counted drain (B01[t+1] confirmed; B23/A[t+1] in flight) */ \
    VMCNT3; \
    BARRIER; \
    LGKM2; SCHED0; \
    PRIO1; HC(4, 0, a47, 0, b01); PRIO0; SCHED0; \
    LGKM0; SCHED0; \
    PRIO1; HC(6, 0, a47, 2, b01); PRIO0; SCHED0; \
    if (s1) { b01[0] = DSRI<0>(pBn); b01[1] = DSRI<1024>(pBn); } \
    /* ---- ph4 ---- */ \
    BARRIER; \
    if (s2) { GB01(CUR, kt2); } \
    PRIO1; HC(4, 2, a47, 0, b23); HC(6, 2, a47, 2, b23); PRIO0; SCHED0; \
    if (s2) { VMCNT1; } else { VMCNT0; } \
}

    for (int t = 0; t < NT; t += 2) {
        TILE_BODY(t,     0, 1, pA0, pB0, pB1);
        TILE_BODY(t + 1, 1, 0, pA1, pB1, pB0);
    }
#undef TILE_BODY

    // ----- epilogue: C/D layout col = lane&15, row = (lane>>4)*4 + j.
    float bv[4];
#pragma unroll
    for (int n = 0; n < 4; ++n) bv[n] = bias[bcol + wc * 64 + n * 16 + fr];
#pragma unroll
    for (int m = 0; m < 8; ++m) {
        const long rbase = brow + wr * 128 + m * 16 + fq * 4;
        float sc[4];
        *reinterpret_cast<float4*>(sc) =
            *reinterpret_cast<const float4*>(scales + rbase);
#pragma unroll
        for (int n = 0; n < 4; ++n) {
            const long cg = bcol + wc * 64 + n * 16 + fr;
#pragma unroll
            for (int j = 0; j < 4; ++j)
                C[(rbase + j) * (long)N_DIM + cg] =
                    (float)acc[m][n][j] * sc[j] + bv[n];
        }
    }
}

// ---------- naive fallback ----------

__global__ __launch_bounds__(256) void naive_kernel(
    const float* __restrict__ x, const float* __restrict__ w,
    const float* __restrict__ bias, float* __restrict__ out, long total) {
    long gid = (long)blockIdx.x * blockDim.x + threadIdx.x;
    if (gid >= total) return;
    long m = gid / N_DIM, n = gid % N_DIM;
    const float* xr = x + m * (long)K_DIM;
    const float* wr = w + n * (long)K_DIM;
    float s = 0.f;
    for (int k = 0; k < K_DIM; ++k) {
        float wv = wr[k];
        float sg = (wv > 0.f) ? 1.f : ((wv < 0.f) ? -1.f : 0.f);
        s += xr[k] * sg;
    }
    out[gid] = s + bias[n];
}

// ---------- launch ----------

extern "C" void kernel_launch(void* const* d_in, const int* in_sizes, int n_in,
                              void* d_out, int out_size, void* d_ws, size_t ws_size,
                              hipStream_t stream) {
    const float* x    = (const float*)d_in[0];
    const float* w    = (const float*)d_in[1];
    const float* bias = (const float*)d_in[2];
    float* out = (float*)d_out;

    const size_t nA = (size_t)M_DIM * K_DIM;  // 33.5M
    const size_t nB = (size_t)N_DIM * K_DIM;  // 16.8M
    const size_t need = nA + nB + M_DIM * sizeof(float) + 64;

    if (ws_size >= need) {
        signed char* xb = (signed char*)d_ws;
        signed char* wb = xb + nA;
        float* scales = (float*)(wb + nB);

        cvt_fused<<<M_DIM + N_DIM, 256, 0, stream>>>(x, w, xb, wb, scales);

        dim3 grid((M_DIM / BM) * (N_DIM / BN));  // 512
        gemm256q<<<grid, 512, 0, stream>>>(xb, wb, scales, bias, out);
    } else {
        long total = (long)M_DIM * N_DIM;
        naive_kernel<<<(int)((total + 255) / 256), 256, 0, stream>>>(x, w, bias, out, total);
    }
}

// Round 21
// 178.289 us; speedup vs baseline: 1.0117x; 1.0117x over previous
//
#include <hip/hip_runtime.h>
#include <hip/hip_bf16.h>

// out[B,S,D_OUT] = x @ sign(W)^T + bias  ==  GEMM M=8192, N=4096, K=4096.
// Round 21: R19 with barriers halved (4 -> 2 per K-tile). Same read batches,
// counted-lgkm splits, and stage set as the proven R18 schedule; phases
// ph1+ph2 and ph3+ph4 merged so wave-slip windows double (16 MFMA + 10 reads
// per window) -> more cross-wave LDS||MFMA overlap. R20's stagger removed
// (neutral). Full ledger re-verified at t=0 / steady / NT-2 / NT-1.

#define M_DIM 8192
#define N_DIM 4096
#define K_DIM 4096
#define BM 256
#define BN 256
#define BK 64
#define NT (K_DIM / BK)  // 64

typedef __attribute__((ext_vector_type(4))) int i32x4;

// ---------- fused conversion kernel ----------

__device__ __forceinline__ signed char sgn_i8(float f) {
    return (f > 0.f) ? 1 : ((f < 0.f) ? -1 : 0);
}

__global__ __launch_bounds__(256) void cvt_fused(
    const float* __restrict__ x, const float* __restrict__ w,
    signed char* __restrict__ xb, signed char* __restrict__ wb,
    float* __restrict__ scales) {
    const int b   = blockIdx.x;
    const int tid = threadIdx.x;

    if (b < M_DIM) {
        const float4* xr4 = reinterpret_cast<const float4*>(x + (long)b * K_DIM);
        __shared__ float red[4];
        float4 v[4];
        float mx = 0.f;
#pragma unroll
        for (int i = 0; i < 4; ++i) {
            v[i] = xr4[tid + i * 256];
            mx = fmaxf(mx, fmaxf(fmaxf(fabsf(v[i].x), fabsf(v[i].y)),
                                 fmaxf(fabsf(v[i].z), fabsf(v[i].w))));
        }
#pragma unroll
        for (int o = 1; o < 64; o <<= 1) mx = fmaxf(mx, __shfl_xor(mx, o));
        if ((tid & 63) == 0) red[tid >> 6] = mx;
        __syncthreads();
        float rmax = fmaxf(fmaxf(red[0], red[1]), fmaxf(red[2], red[3]));
        const float inv = (rmax > 0.f) ? (127.f / rmax) : 0.f;

        char4* qr = reinterpret_cast<char4*>(xb + (long)b * K_DIM);
#pragma unroll
        for (int i = 0; i < 4; ++i) {
            char4 c;
            c.x = (signed char)__float2int_rn(fminf(fmaxf(v[i].x * inv, -127.f), 127.f));
            c.y = (signed char)__float2int_rn(fminf(fmaxf(v[i].y * inv, -127.f), 127.f));
            c.z = (signed char)__float2int_rn(fminf(fmaxf(v[i].z * inv, -127.f), 127.f));
            c.w = (signed char)__float2int_rn(fminf(fmaxf(v[i].w * inv, -127.f), 127.f));
            qr[tid + i * 256] = c;
        }
        if (tid == 0) scales[b] = (rmax > 0.f) ? (rmax * (1.f / 127.f)) : 0.f;
    } else {
        const long i = (long)(b - M_DIM) * 256 + tid;  // vec16 index
        const float4* p = reinterpret_cast<const float4*>(w) + i * 4;
        int4 r;
        signed char* rc = (signed char*)&r;
#pragma unroll
        for (int k = 0; k < 4; ++k) {
            float4 vv = p[k];
            rc[k * 4 + 0] = sgn_i8(vv.x);
            rc[k * 4 + 1] = sgn_i8(vv.y);
            rc[k * 4 + 2] = sgn_i8(vv.z);
            rc[k * 4 + 3] = sgn_i8(vv.w);
        }
        reinterpret_cast<int4*>(wb)[i] = r;
    }
}

// ---------- async global->LDS ----------

__device__ __forceinline__ void GL16(const void* g, void* l) {
    __builtin_amdgcn_global_load_lds(
        (const __attribute__((address_space(1))) unsigned int*)g,
        (__attribute__((address_space(3))) unsigned int*)l, 16, 0, 0);
}

// ---------- inline-asm ds_read_b128 (i32x4) ----------

template<int OFS>
__device__ __forceinline__ i32x4 DSRI(const signed char* p) {
    i32x4 r;
    auto lp = (const __attribute__((address_space(3))) signed char*)p;
    asm volatile("ds_read_b128 %0, %1 offset:%2"
                 : "=&v"(r) : "v"(lp), "i"(OFS));
    return r;
}

#define BARRIER asm volatile("s_barrier" ::: "memory")
#define VMCNT0  asm volatile("s_waitcnt vmcnt(0)" ::: "memory")
#define VMCNT1  asm volatile("s_waitcnt vmcnt(1)" ::: "memory")
#define VMCNT3  asm volatile("s_waitcnt vmcnt(3)" ::: "memory")
#define LGKM0   asm volatile("s_waitcnt lgkmcnt(0)" ::: "memory")
#define LGKM2   asm volatile("s_waitcnt lgkmcnt(2)" ::: "memory")
#define LGKM4   asm volatile("s_waitcnt lgkmcnt(4)" ::: "memory")
#define SCHED0  __builtin_amdgcn_sched_barrier(0)
#define PRIO1   __builtin_amdgcn_s_setprio(1)
#define PRIO0   __builtin_amdgcn_s_setprio(0)

// 4-MFMA cell: 2 m-frags x 2 n-frags, K=64 in one MFMA each.
#define HC(MB, NB, Af, AOFS, Bf) \
    _Pragma("unroll") for (int m_ = 0; m_ < 2; ++m_) \
    _Pragma("unroll") for (int n_ = 0; n_ < 2; ++n_) \
        acc[(MB) + m_][(NB) + n_] = __builtin_amdgcn_mfma_i32_16x16x64_i8( \
            Af[(AOFS) + m_], Bf[n_], acc[(MB) + m_][(NB) + n_], 0, 0, 0)

// ---------- 256x256 2-barrier i8 GEMM ----------
// 512 thr = 8 waves (2M x 4N); wave out 128x64 = 8x4 16x16 frags; 32 MFMA/tile.
// LDS: As/Bs [2][256 rows][64B] = 64 KiB (2 blocks/CU). Swizzle: row r's
// 16B-chunk g at phys g ^ ((r>>1)&3); inverse-swizzled global src, same XOR
// on reads (R18-verified, 0 conflicts).
// Per K-tile t (CUR=t&1):
//  half A: BAR | stage B23+A03+A47(t+1)->NXT | rd a03 x4 | LGKM(2)
//          | 8 MFMA (a03x b01) | LGKM(0) | 8 MFMA | rd b23 x2 + a47 x4
//          | LGKM(4) [b23] | 8 MFMA (a03 x b23) | LGKM(0) [a47]
//          | 8 MFMA (a47 x b01) | VMCNT(3) [drains B01(t+1)]
//  half B: BAR | stage B01(t+2)->CUR | rd b01(t+1) x2
//          | 8 MFMA (a47 x b23) | VMCNT(s2?1:0) [drains B23/A03/A47(t+1)]
// vmcnt ledger (in-order): enter t: 1 (B01[t+1]); top +3 = 4 -> VMCNT(3)
// drains B01[t+1]; mid +1 (B01[t+2]) = 4 -> VMCNT(1) drains the 3 t+1 units.
// lgkm ledger: enter t: 2 (b01 pre-issued); +4 a03 = 6 -> LGKM(2) certifies
// b01+a03[0,1]; LGKM(0) -> a03[2,3]; +6 -> LGKM(4) certifies b23; LGKM(0)
// -> a47. Stage-vs-read windows all barrier-separated (audited).

__global__ __launch_bounds__(512, 2) void gemm256r(
    const signed char* __restrict__ A,   // [M][K] i8 (quantized x)
    const signed char* __restrict__ Bt,  // [N][K] i8 (sign weights)
    const float* __restrict__ scales,    // [M] rowmax/127
    const float* __restrict__ bias,      // [N]
    float* __restrict__ C)               // [M][N] fp32
{
    __shared__ __align__(16) signed char As[2][BM * BK];  // 2 x 16 KiB
    __shared__ __align__(16) signed char Bs[2][BN * BK];  // 2 x 16 KiB

    const int tid  = threadIdx.x;
    const int lane = tid & 63;
    const int w    = tid >> 6;
    const int wr   = w >> 2;
    const int wc   = w & 3;

    // T1: XCD-aware bijective swizzle (grid = 512, divisible by 8)
    int bid = blockIdx.x;
    const int cpx = gridDim.x >> 3;
    bid = (bid & 7) * cpx + (bid >> 3);
    const int ntile = N_DIM / BN;  // 16
    const long brow = (long)(bid / ntile) * BM;
    const long bcol = (long)(bid % ntile) * BN;

    // ----- staging: each GL16/wave = 16 rows x 64B; lane l -> row l>>2,
    // phys chunk l&3; global col chunk g = (l&3) ^ ((l>>3)&3)  [row>>1 swz].
    const int lrow  = lane >> 2;
    const int gcol  = ((lane & 3) ^ ((lane >> 3) & 3)) * 16;  // i8 elements
    const int rA03u = (w >> 2) * 128 + (w & 3) * 16;          // wave-uniform
    const int rB01u = (w >> 1) * 64 + (w & 1) * 16;
    const long gA03 = brow + rA03u + lrow;
    const long gB01 = bcol + rB01u + lrow;

#define GA03(BUF, KT) GL16(A  + (gA03)      * (long)K_DIM + (gcol + (KT)), &As[BUF][(rA03u)      * 64])
#define GA47(BUF, KT) GL16(A  + (gA03 + 64) * (long)K_DIM + (gcol + (KT)), &As[BUF][(rA03u + 64) * 64])
#define GB01(BUF, KT) GL16(Bt + (gB01)      * (long)K_DIM + (gcol + (KT)), &Bs[BUF][(rB01u)      * 64])
#define GB23(BUF, KT) GL16(Bt + (gB01 + 32) * (long)K_DIM + (gcol + (KT)), &Bs[BUF][(rB01u + 32) * 64])

    // ----- fragment reads: row = base + (lane&15), k-chunk g = lane>>4,
    // phys chunk = g ^ ((row>>1)&3) = (lane>>4) ^ ((lane>>1)&3)  [base%16==0].
    const int fr = lane & 15;
    const int fq = lane >> 4;
    const int pch = (fq ^ ((lane >> 1) & 3)) * 16;  // bytes
    const int aoffB = (wr * 128 + fr) * 64 + pch;
    const int boffB = (wc * 64 + fr) * 64 + pch;

    const signed char* pA0 = &As[0][aoffB];
    const signed char* pA1 = &As[1][aoffB];
    const signed char* pB0 = &Bs[0][boffB];
    const signed char* pB1 = &Bs[1][boffB];

    i32x4 acc[8][4];
#pragma unroll
    for (int m = 0; m < 8; ++m)
#pragma unroll
        for (int n = 0; n < 4; ++n) acc[m][n] = (i32x4){0, 0, 0, 0};

    i32x4 a03[4], a47[4], b01[2], b23[2];

    // ----- prologue: tile0 (4 GL16) + tile1's B01 (1 GL16) -----
    GA03(0, 0); GA47(0, 0); GB01(0, 0); GB23(0, 0);
    GB01(1, BK);
    VMCNT0;
    BARRIER;
    b01[0] = DSRI<0>(pB0);
    b01[1] = DSRI<1024>(pB0);

#define TILE_BODY(TT, CUR, NXT, pAc, pBc, pBn) { \
    const long kt1 = (long)((TT) + 1) * BK; \
    const long kt2 = (long)((TT) + 2) * BK; \
    const bool s1 = ((TT) + 1 < NT); \
    const bool s2 = ((TT) + 2 < NT); \
    /* ---- half A ---- */ \
    BARRIER; \
    if (s1) { GB23(NXT, kt1); GA03(NXT, kt1); GA47(NXT, kt1); } \
    a03[0] = DSRI<0>(pAc);    a03[1] = DSRI<1024>(pAc); \
    a03[2] = DSRI<2048>(pAc); a03[3] = DSRI<3072>(pAc); \
    LGKM2; SCHED0; \
    PRIO1; HC(0, 0, a03, 0, b01); PRIO0; SCHED0; \
    LGKM0; SCHED0; \
    PRIO1; HC(2, 0, a03, 2, b01); PRIO0; SCHED0; \
    b23[0] = DSRI<2048>(pBc); b23[1] = DSRI<3072>(pBc); \
    a47[0] = DSRI<4096>(pAc); a47[1] = DSRI<5120>(pAc); \
    a47[2] = DSRI<6144>(pAc); a47[3] = DSRI<7168>(pAc); \
    LGKM4; SCHED0; \
    PRIO1; HC(0, 2, a03, 0, b23); HC(2, 2, a03, 2, b23); PRIO0; SCHED0; \
    LGKM0; SCHED0; \
    PRIO1; HC(4, 0, a47, 0, b01); HC(6, 0, a47, 2, b01); PRIO0; SCHED0; \
    VMCNT3; \
    /* ---- half B ---- */ \
    BARRIER; \
    if (s2) { GB01(CUR, kt2); } \
    if (s1) { b01[0] = DSRI<0>(pBn); b01[1] = DSRI<1024>(pBn); } \
    PRIO1; HC(4, 2, a47, 0, b23); HC(6, 2, a47, 2, b23); PRIO0; SCHED0; \
    if (s2) { VMCNT1; } else { VMCNT0; } \
}

    for (int t = 0; t < NT; t += 2) {
        TILE_BODY(t,     0, 1, pA0, pB0, pB1);
        TILE_BODY(t + 1, 1, 0, pA1, pB1, pB0);
    }
#undef TILE_BODY

    // ----- epilogue: C/D layout col = lane&15, row = (lane>>4)*4 + j.
    // out = acc_i32 * scale[row] + bias[col]  (acc exact; |acc| < 2^24).
    float bv[4];
#pragma unroll
    for (int n = 0; n < 4; ++n) bv[n] = bias[bcol + wc * 64 + n * 16 + fr];
#pragma unroll
    for (int m = 0; m < 8; ++m) {
        const long rbase = brow + wr * 128 + m * 16 + fq * 4;
        float sc[4];
        *reinterpret_cast<float4*>(sc) =
            *reinterpret_cast<const float4*>(scales + rbase);
#pragma unroll
        for (int n = 0; n < 4; ++n) {
            const long cg = bcol + wc * 64 + n * 16 + fr;
#pragma unroll
            for (int j = 0; j < 4; ++j)
                C[(rbase + j) * (long)N_DIM + cg] =
                    (float)acc[m][n][j] * sc[j] + bv[n];
        }
    }
}

// ---------- naive fallback ----------

__global__ __launch_bounds__(256) void naive_kernel(
    const float* __restrict__ x, const float* __restrict__ w,
    const float* __restrict__ bias, float* __restrict__ out, long total) {
    long gid = (long)blockIdx.x * blockDim.x + threadIdx.x;
    if (gid >= total) return;
    long m = gid / N_DIM, n = gid % N_DIM;
    const float* xr = x + m * (long)K_DIM;
    const float* wr = w + n * (long)K_DIM;
    float s = 0.f;
    for (int k = 0; k < K_DIM; ++k) {
        float wv = wr[k];
        float sg = (wv > 0.f) ? 1.f : ((wv < 0.f) ? -1.f : 0.f);
        s += xr[k] * sg;
    }
    out[gid] = s + bias[n];
}

// ---------- launch ----------

extern "C" void kernel_launch(void* const* d_in, const int* in_sizes, int n_in,
                              void* d_out, int out_size, void* d_ws, size_t ws_size,
                              hipStream_t stream) {
    const float* x    = (const float*)d_in[0];
    const float* w    = (const float*)d_in[1];
    const float* bias = (const float*)d_in[2];
    float* out = (float*)d_out;

    const size_t nA = (size_t)M_DIM * K_DIM;  // 33.5M
    const size_t nB = (size_t)N_DIM * K_DIM;  // 16.8M
    const size_t need = nA + nB + M_DIM * sizeof(float) + 64;

    if (ws_size >= need) {
        signed char* xb = (signed char*)d_ws;
        signed char* wb = xb + nA;
        float* scales = (float*)(wb + nB);

        cvt_fused<<<M_DIM + N_DIM, 256, 0, stream>>>(x, w, xb, wb, scales);

        dim3 grid((M_DIM / BM) * (N_DIM / BN));  // 512
        gemm256r<<<grid, 512, 0, stream>>>(xb, wb, scales, bias, out);
    } else {
        long total = (long)M_DIM * N_DIM;
        naive_kernel<<<(int)((total + 255) / 256), 256, 0, stream>>>(x, w, bias, out, total);
    }
}